// Round 8
// baseline (1466.327 us; speedup 1.0000x reference)
//
#include <hip/hip_runtime.h>
#include <hip/hip_bf16.h>

#define GN 16384
#define GD 128
#define KSPLIT 4
#define KBLK (GN / KSPLIT)     // 4096 k per block
#define NSTEP (KBLK / 32)      // 128 32-k steps per wave
#define OUT_ELEMS (GN * GD)

typedef __attribute__((ext_vector_type(8))) short short8;
typedef __attribute__((ext_vector_type(4))) float floatx4;
typedef __attribute__((ext_vector_type(4))) int intx4;

static __device__ __forceinline__ unsigned short f32_to_bf16(float f) {
  unsigned u = __builtin_bit_cast(unsigned, f);
  unsigned r = u + 0x7FFFu + ((u >> 16) & 1u);  // RNE (inputs finite/normal)
  return (unsigned short)(r >> 16);
}

// Kernel 1: xT2 = x in MFMA B-fragment order.
// For 32-k step g (0..511), col-tile cc (0..7), lane=(q,m):
//   xT2[((g*8+cc)*64+lane)*8 + j] = bf16( x[g*32 + q*8 + j][cc*16 + m] )
// One block per g; 4 MiB total, L2/L3-resident for the gemm.
__global__ __launch_bounds__(256) void prep_kernel(const float* __restrict__ x,
                                                   unsigned short* __restrict__ xT2) {
  __shared__ unsigned short t[32][130];  // pad->stride 260B: phase-2 reads 2-way (free)
  const int g = blockIdx.x;
  const int tid = threadIdx.x;
  const float* xs = x + (size_t)g * 32 * GD;
#pragma unroll
  for (int i = 0; i < 16; ++i) {
    int e = tid + 256 * i;  // 0..4095
    t[e >> 7][e & 127] = f32_to_bf16(xs[e]);
  }
  __syncthreads();
  unsigned short* og = xT2 + (size_t)g * 4096;
#pragma unroll
  for (int h = 0; h < 2; ++h) {
    int f = tid + 256 * h;  // fragment id = cc*64 + lane, 0..511
    int cc = f >> 6, ln = f & 63, qq = ln >> 4, mm = ln & 15;
    short8 v;
#pragma unroll
    for (int j = 0; j < 8; ++j) v[j] = (short)t[qq * 8 + j][cc * 16 + mm];
    *(short8*)(og + (size_t)f * 8) = v;  // coalesced 16B/lane
  }
}

// Kernel 2: partial[ks] = adj[rows, kslice] @ x. NO LDS, NO barriers.
// 256 thr / 4 independent waves; wave owns 32 rows (m, m+16 tiles) x full D x 4096 k.
// adj: nontemporal coalesced dwordx4 (keeps xT2 in L2); B: one coalesced 1KB wave
// load per fragment from pre-permuted xT2. Register prefetch one step ahead on both
// streams -> the CU load queue never drains.
__global__ __launch_bounds__(256, 2) void gemm_kernel(const int* __restrict__ adj,
                                                      const unsigned short* __restrict__ xT2,
                                                      float* __restrict__ partials) {
  const int tid = threadIdx.x;
  const int wave = tid >> 6;
  const int lane = tid & 63;
  const int q = lane >> 4;   // 0..3
  const int m = lane & 15;   // 0..15
  const int rbase = blockIdx.x * 128 + wave * 32;
  const int ks = blockIdx.y;
  const int kbase = ks * KBLK;

  const int* a0 = adj + (size_t)(rbase + m) * GN + kbase + q * 8;
  const int* a1 = a0 + (size_t)16 * GN;
  // fragment base for this k-slice: step g0 = kbase/32, cc=0, this lane
  const unsigned short* bp = xT2 + (size_t)(kbase / 32) * 4096 + (size_t)lane * 8;

  floatx4 acc[2][8];
#pragma unroll
  for (int t = 0; t < 2; ++t)
#pragma unroll
    for (int c = 0; c < 8; ++c) acc[t][c] = (floatx4){0.f, 0.f, 0.f, 0.f};

  // prefetch step 0
  intx4 r0 = __builtin_nontemporal_load((const intx4*)(a0));
  intx4 r1 = __builtin_nontemporal_load((const intx4*)(a0 + 4));
  intx4 r2 = __builtin_nontemporal_load((const intx4*)(a1));
  intx4 r3 = __builtin_nontemporal_load((const intx4*)(a1 + 4));
  short8 bf[8];
#pragma unroll
  for (int c = 0; c < 8; ++c) bf[c] = *(const short8*)(bp + c * 512);

  for (int gl = 0; gl < NSTEP; ++gl) {
    const int nk = ((gl + 1) & (NSTEP - 1)) * 32;           // wraps on last (discarded)
    const unsigned short* bn = bp + ((gl + 1) & (NSTEP - 1)) * 4096;

    // prefetch next step (both streams)
    intx4 s0 = __builtin_nontemporal_load((const intx4*)(a0 + nk));
    intx4 s1 = __builtin_nontemporal_load((const intx4*)(a0 + nk + 4));
    intx4 s2 = __builtin_nontemporal_load((const intx4*)(a1 + nk));
    intx4 s3 = __builtin_nontemporal_load((const intx4*)(a1 + nk + 4));
    short8 nbf[8];
#pragma unroll
    for (int c = 0; c < 8; ++c) nbf[c] = *(const short8*)(bn + c * 512);

    // adj 0/1 int -> bf16 0x0000/0x3F80 (two elems per dword)
    intx4 p0, p1;
    p0.x = (r0.x | (r0.y << 16)) * 0x3F80;
    p0.y = (r0.z | (r0.w << 16)) * 0x3F80;
    p0.z = (r1.x | (r1.y << 16)) * 0x3F80;
    p0.w = (r1.z | (r1.w << 16)) * 0x3F80;
    p1.x = (r2.x | (r2.y << 16)) * 0x3F80;
    p1.y = (r2.z | (r2.w << 16)) * 0x3F80;
    p1.z = (r3.x | (r3.y << 16)) * 0x3F80;
    p1.w = (r3.z | (r3.w << 16)) * 0x3F80;
    const short8 af0 = __builtin_bit_cast(short8, p0);
    const short8 af1 = __builtin_bit_cast(short8, p1);

#pragma unroll
    for (int c = 0; c < 8; ++c) {
      acc[0][c] = __builtin_amdgcn_mfma_f32_16x16x32_bf16(af0, bf[c], acc[0][c], 0, 0, 0);
      acc[1][c] = __builtin_amdgcn_mfma_f32_16x16x32_bf16(af1, bf[c], acc[1][c], 0, 0, 0);
    }

    r0 = s0; r1 = s1; r2 = s2; r3 = s3;
#pragma unroll
    for (int c = 0; c < 8; ++c) bf[c] = nbf[c];
  }

  // Epilogue: plain stores. C/D: col=lane&15, row=q*4+reg.
  float* pp = partials + (size_t)ks * OUT_ELEMS + (size_t)rbase * GD;
#pragma unroll
  for (int t = 0; t < 2; ++t)
#pragma unroll
    for (int c = 0; c < 8; ++c)
#pragma unroll
      for (int r = 0; r < 4; ++r)
        pp[(size_t)(t * 16 + q * 4 + r) * GD + c * 16 + m] = acc[t][c][r];
}

// Kernel 3: out = x + sum of 4 partials (also un-poisons d_out)
__global__ __launch_bounds__(256) void reduce_kernel(const float* __restrict__ x,
                                                     const float* __restrict__ partials,
                                                     float* __restrict__ out) {
  size_t i = ((size_t)blockIdx.x * 256 + threadIdx.x) * 4;
  floatx4 v = *(const floatx4*)(x + i);
  v += *(const floatx4*)(partials + 0 * (size_t)OUT_ELEMS + i);
  v += *(const floatx4*)(partials + 1 * (size_t)OUT_ELEMS + i);
  v += *(const floatx4*)(partials + 2 * (size_t)OUT_ELEMS + i);
  v += *(const floatx4*)(partials + 3 * (size_t)OUT_ELEMS + i);
  *(floatx4*)(out + i) = v;
}

extern "C" void kernel_launch(void* const* d_in, const int* in_sizes, int n_in,
                              void* d_out, int out_size, void* d_ws, size_t ws_size,
                              hipStream_t stream) {
  const float* x = (const float*)d_in[0];
  const int* adj = (const int*)d_in[1];
  float* out = (float*)d_out;
  unsigned short* xT2 = (unsigned short*)d_ws;                    // 4 MiB
  float* partials = (float*)((char*)d_ws + (size_t)GN * GD * 2);  // 4 x 8 MiB

  prep_kernel<<<GN / 32, 256, 0, stream>>>(x, xT2);
  gemm_kernel<<<dim3(GN / 128, KSPLIT), 256, 0, stream>>>(adj, xT2, partials);
  reduce_kernel<<<OUT_ELEMS / 4 / 256, 256, 0, stream>>>(x, partials, out);
}

// Round 9
// 1350.887 us; speedup vs baseline: 1.0855x; 1.0855x over previous
//
#include <hip/hip_runtime.h>
#include <hip/hip_bf16.h>

#define GN 16384
#define GD 128
#define KSPLIT 4
#define KBLK (GN / KSPLIT)        // 4096 k per block
#define PHK 128                   // k per LDS phase
#define NPH (KBLK / PHK)          // 32 phases
#define NSTEP (PHK / 32)          // 4 mfma k-steps per phase
#define BUF_SHORTS (GD * PHK)     // 16384 shorts = 32 KB per buffer
#define OUT_ELEMS (GN * GD)

typedef __attribute__((ext_vector_type(8))) short short8;
typedef __attribute__((ext_vector_type(4))) float floatx4;
typedef __attribute__((ext_vector_type(4))) int intx4;

static __device__ __forceinline__ unsigned short f32_to_bf16(float f) {
  unsigned u = __builtin_bit_cast(unsigned, f);
  unsigned r = u + 0x7FFFu + ((u >> 16) & 1u);  // RNE (inputs finite/normal)
  return (unsigned short)(r >> 16);
}

// Kernel 1: xT[d][j] <- bf16(x[j][d])  (4 MiB, L2/L3-resident)
__global__ __launch_bounds__(256) void prep_kernel(const float* __restrict__ x,
                                                   unsigned short* __restrict__ xT) {
  __shared__ unsigned short t[GD][66];
  const int tid = threadIdx.x;
  const int j0 = blockIdx.x * 64;
  for (int i = tid; i < 64 * GD; i += 256) {
    int j = i >> 7, d = i & (GD - 1);
    t[d][j] = f32_to_bf16(x[(size_t)(j0 + j) * GD + d]);
  }
  __syncthreads();
  for (int i = tid; i < GD * 32; i += 256) {
    int d = i >> 5, jp = i & 31;
    unsigned lo = t[d][2 * jp], hi = t[d][2 * jp + 1];
    *reinterpret_cast<unsigned*>(xT + (size_t)d * GN + j0 + 2 * jp) = lo | (hi << 16);
  }
}

// Kernel 2: R6 structure + PER-BLOCK K-PHASE ROTATION (the experiment).
// All blocks previously advanced through identical low-address column windows in
// lockstep (64KB row stride -> same low 15 addr bits device-wide) => HBM channel
// camping. Each block now starts at physical phase rot=((bx*4+ks)*33)&31 and wraps,
// spreading 512 blocks uniformly over the 128 column-step positions.
__global__ __launch_bounds__(512, 4) void gemm_kernel(const int* __restrict__ adj,
                                                      const unsigned short* __restrict__ xT,
                                                      float* __restrict__ partials) {
  __shared__ unsigned short bbuf[2][BUF_SHORTS];  // 2 x 32 KB
  const int tid = threadIdx.x;
  const int wave = tid >> 6;
  const int lane = tid & 63;
  const int q = lane >> 4;   // 0..3
  const int m = lane & 15;   // 0..15
  const int rbase = blockIdx.x * 128 + wave * 16;
  const int ks = blockIdx.y;
  const int kbase = ks * KBLK;
  const int rot = ((blockIdx.x * 4 + ks) * 33) & (NPH - 1);  // phase rotation

  // staging: 4 granules (16 B) per thread; slot s = tid + 512p; row n = s>>4
  const unsigned short* gptr[4];
  unsigned short* lptr[4];
#pragma unroll
  for (int p = 0; p < 4; ++p) {
    int s = tid + 512 * p;            // 0..2047
    int n = s >> 4;                   // B row (= d) 0..127
    int gsrc = (s & 15) ^ (n & 7);    // XOR swizzle (involution on low 3 bits)
    gptr[p] = xT + (size_t)n * GN + kbase + gsrc * 8;
    lptr[p] = &bbuf[0][0] + (size_t)s * 8;
  }

#define STAGE(bufsel, koff)                                                             \
  do {                                                                                  \
    _Pragma("unroll") for (int p = 0; p < 4; ++p) {                                     \
      __builtin_amdgcn_global_load_lds(                                                 \
          (const __attribute__((address_space(1))) unsigned int*)(gptr[p] + (koff)),    \
          (__attribute__((address_space(3))) unsigned int*)(lptr[p] +                   \
                                                           (bufsel) * BUF_SHORTS),      \
          16, 0, 0);                                                                    \
    }                                                                                   \
  } while (0)

  const int* a0 = adj + (size_t)(rbase + m) * GN + kbase + q * 8;

  floatx4 acc[8];
#pragma unroll
  for (int c = 0; c < 8; ++c) acc[c] = (floatx4){0.f, 0.f, 0.f, 0.f};

  STAGE(0, rot * PHK);
  intx4 ca0 = *(const intx4*)(a0 + rot * PHK);
  intx4 ca1 = *(const intx4*)(a0 + rot * PHK + 4);

  int buf = 0;
  for (int ph = 0; ph < NPH; ++ph) {
    __syncthreads();  // staged buf complete; all waves done with buf^1
    if (ph + 1 < NPH) STAGE(buf ^ 1, ((ph + 1 + rot) & (NPH - 1)) * PHK);

#pragma unroll
    for (int st = 0; st < NSTEP; ++st) {
      const int g = ph * NSTEP + st;   // logical 32-k step 0..127
      // physical offset of the NEXT logical step (wraps to rot's start; discarded)
      const int gn = g + 1;
      const int nk = ((((gn >> 2) + rot) & (NPH - 1)) * NSTEP + (gn & 3)) * 32;
      intx4 na0 = *(const intx4*)(a0 + nk);
      intx4 na1 = *(const intx4*)(a0 + nk + 4);

      // B frags: lane(q,m), col-tile cc -> row n=cc*16+m, granule (st*4+q)^(m&7)
      short8 bf[8];
      const unsigned short* bb = &bbuf[buf][0] + (((st * 4 + q) ^ (m & 7)) * 8);
#pragma unroll
      for (int cc = 0; cc < 8; ++cc)
        bf[cc] = *(const short8*)(bb + (cc * 16 + m) * PHK);

      // adj 0/1 int -> bf16 0x0000/0x3F80 (two elems per dword)
      intx4 pk;
      pk.x = (ca0.x | (ca0.y << 16)) * 0x3F80;
      pk.y = (ca0.z | (ca0.w << 16)) * 0x3F80;
      pk.z = (ca1.x | (ca1.y << 16)) * 0x3F80;
      pk.w = (ca1.z | (ca1.w << 16)) * 0x3F80;
      const short8 af = __builtin_bit_cast(short8, pk);

#pragma unroll
      for (int cc = 0; cc < 8; ++cc)
        acc[cc] = __builtin_amdgcn_mfma_f32_16x16x32_bf16(af, bf[cc], acc[cc], 0, 0, 0);

      ca0 = na0;
      ca1 = na1;
    }
    buf ^= 1;
  }

  // Epilogue: plain stores. C/D: col=lane&15, row=q*4+reg.
  float* pp = partials + (size_t)ks * OUT_ELEMS + (size_t)rbase * GD;
#pragma unroll
  for (int cc = 0; cc < 8; ++cc)
#pragma unroll
    for (int r = 0; r < 4; ++r)
      pp[(size_t)(q * 4 + r) * GD + cc * 16 + m] = acc[cc][r];
}

// Kernel 3: out = x + sum of 4 partials (also un-poisons d_out)
__global__ __launch_bounds__(256) void reduce_kernel(const float* __restrict__ x,
                                                     const float* __restrict__ partials,
                                                     float* __restrict__ out) {
  size_t i = ((size_t)blockIdx.x * 256 + threadIdx.x) * 4;
  floatx4 v = *(const floatx4*)(x + i);
  v += *(const floatx4*)(partials + 0 * (size_t)OUT_ELEMS + i);
  v += *(const floatx4*)(partials + 1 * (size_t)OUT_ELEMS + i);
  v += *(const floatx4*)(partials + 2 * (size_t)OUT_ELEMS + i);
  v += *(const floatx4*)(partials + 3 * (size_t)OUT_ELEMS + i);
  *(floatx4*)(out + i) = v;
}

extern "C" void kernel_launch(void* const* d_in, const int* in_sizes, int n_in,
                              void* d_out, int out_size, void* d_ws, size_t ws_size,
                              hipStream_t stream) {
  const float* x = (const float*)d_in[0];
  const int* adj = (const int*)d_in[1];
  float* out = (float*)d_out;
  unsigned short* xT = (unsigned short*)d_ws;                     // 4 MiB
  float* partials = (float*)((char*)d_ws + (size_t)GN * GD * 2);  // 4 x 8 MiB

  prep_kernel<<<GN / 64, 256, 0, stream>>>(x, xT);
  gemm_kernel<<<dim3(GN / 128, KSPLIT), 512, 0, stream>>>(adj, xT, partials);
  reduce_kernel<<<OUT_ELEMS / 4 / 256, 256, 0, stream>>>(x, partials, out);
}

// Round 10
// 1346.893 us; speedup vs baseline: 1.0887x; 1.0030x over previous
//
#include <hip/hip_runtime.h>
#include <hip/hip_bf16.h>

#define GN 16384
#define GD 128
#define KSPLIT 4
#define KBLK (GN / KSPLIT)        // 4096 k per block
#define PHK 128                   // k per LDS phase
#define NPH (KBLK / PHK)          // 32 phases
#define NSTEP (PHK / 32)          // 4 mfma k-steps per phase
#define BUF_SHORTS (GD * PHK)     // 16384 shorts = 32 KB per buffer
#define OUT_ELEMS (GN * GD)

typedef __attribute__((ext_vector_type(8))) short short8;
typedef __attribute__((ext_vector_type(4))) float floatx4;
typedef __attribute__((ext_vector_type(4))) int intx4;

static __device__ __forceinline__ unsigned short f32_to_bf16(float f) {
  unsigned u = __builtin_bit_cast(unsigned, f);
  unsigned r = u + 0x7FFFu + ((u >> 16) & 1u);  // RNE (inputs finite/normal)
  return (unsigned short)(r >> 16);
}

// Kernel 1: xT[d][j] <- bf16(x[j][d])  (4 MiB, L2/L3-resident)
__global__ __launch_bounds__(256) void prep_kernel(const float* __restrict__ x,
                                                   unsigned short* __restrict__ xT) {
  __shared__ unsigned short t[GD][66];
  const int tid = threadIdx.x;
  const int j0 = blockIdx.x * 64;
  for (int i = tid; i < 64 * GD; i += 256) {
    int j = i >> 7, d = i & (GD - 1);
    t[d][j] = f32_to_bf16(x[(size_t)(j0 + j) * GD + d]);
  }
  __syncthreads();
  for (int i = tid; i < GD * 32; i += 256) {
    int d = i >> 5, jp = i & 31;
    unsigned lo = t[d][2 * jp], hi = t[d][2 * jp + 1];
    *reinterpret_cast<unsigned*>(xT + (size_t)d * GN + j0 + 2 * jp) = lo | (hi << 16);
  }
}

// Kernel 2: R6 structure + PHASE-GRANULAR ADJ REGISTER DOUBLE-BUFFER (the experiment).
// R6 prefetched adj one 32-k step ahead: the last pair issues ~1 step before the
// __syncthreads() vmcnt(0) drain -> ~900-cyc HBM latency partially exposed at EVERY
// barrier. Now all 8 adj loads for phase ph+1 issue right after the barrier (with the
// staging), a full phase before drain/use -> zero exposure. +48 VGPR, fits <=128.
__global__ __launch_bounds__(512, 4) void gemm_kernel(const int* __restrict__ adj,
                                                      const unsigned short* __restrict__ xT,
                                                      float* __restrict__ partials) {
  __shared__ unsigned short bbuf[2][BUF_SHORTS];  // 2 x 32 KB
  const int tid = threadIdx.x;
  const int wave = tid >> 6;
  const int lane = tid & 63;
  const int q = lane >> 4;   // 0..3
  const int m = lane & 15;   // 0..15
  const int rbase = blockIdx.x * 128 + wave * 16;
  const int ks = blockIdx.y;
  const int kbase = ks * KBLK;

  // staging: 4 granules (16 B) per thread; slot s = tid + 512p; row n = s>>4
  const unsigned short* gptr[4];
  unsigned short* lptr[4];
#pragma unroll
  for (int p = 0; p < 4; ++p) {
    int s = tid + 512 * p;            // 0..2047
    int n = s >> 4;                   // B row (= d) 0..127
    int gsrc = (s & 15) ^ (n & 7);    // XOR swizzle (involution on low 3 bits)
    gptr[p] = xT + (size_t)n * GN + kbase + gsrc * 8;
    lptr[p] = &bbuf[0][0] + (size_t)s * 8;
  }

#define STAGE(bufsel, koff)                                                             \
  do {                                                                                  \
    _Pragma("unroll") for (int p = 0; p < 4; ++p) {                                     \
      __builtin_amdgcn_global_load_lds(                                                 \
          (const __attribute__((address_space(1))) unsigned int*)(gptr[p] + (koff)),    \
          (__attribute__((address_space(3))) unsigned int*)(lptr[p] +                   \
                                                           (bufsel) * BUF_SHORTS),      \
          16, 0, 0);                                                                    \
    }                                                                                   \
  } while (0)

  const int* a0 = adj + (size_t)(rbase + m) * GN + kbase + q * 8;

  floatx4 acc[8];
#pragma unroll
  for (int c = 0; c < 8; ++c) acc[c] = (floatx4){0.f, 0.f, 0.f, 0.f};

  // preload phase 0: staging + all 8 adj frag-loads (offsets st*32 + {0,4})
  STAGE(0, 0);
  intx4 cadj[8];
#pragma unroll
  for (int u = 0; u < 8; ++u)
    cadj[u] = *(const intx4*)(a0 + (u >> 1) * 32 + (u & 1) * 4);

  int buf = 0;
  for (int ph = 0; ph < NPH; ++ph) {
    __syncthreads();  // staged buf complete; prior phase's loads long since done
    intx4 nadj[8];
    if (ph + 1 < NPH) {
      STAGE(buf ^ 1, (ph + 1) * PHK);
      const int* an = a0 + (ph + 1) * PHK;
#pragma unroll
      for (int u = 0; u < 8; ++u)
        nadj[u] = *(const intx4*)(an + (u >> 1) * 32 + (u & 1) * 4);
    }

#pragma unroll
    for (int st = 0; st < NSTEP; ++st) {
      // B frags: lane(q,m), col-tile cc -> row n=cc*16+m, granule (st*4+q)^(m&7)
      short8 bf[8];
      const unsigned short* bb = &bbuf[buf][0] + (((st * 4 + q) ^ (m & 7)) * 8);
#pragma unroll
      for (int cc = 0; cc < 8; ++cc)
        bf[cc] = *(const short8*)(bb + (cc * 16 + m) * PHK);

      // adj 0/1 int -> bf16 0x0000/0x3F80 (two elems per dword)
      const intx4 r0 = cadj[2 * st], r1 = cadj[2 * st + 1];
      intx4 pk;
      pk.x = (r0.x | (r0.y << 16)) * 0x3F80;
      pk.y = (r0.z | (r0.w << 16)) * 0x3F80;
      pk.z = (r1.x | (r1.y << 16)) * 0x3F80;
      pk.w = (r1.z | (r1.w << 16)) * 0x3F80;
      const short8 af = __builtin_bit_cast(short8, pk);

#pragma unroll
      for (int cc = 0; cc < 8; ++cc)
        acc[cc] = __builtin_amdgcn_mfma_f32_16x16x32_bf16(af, bf[cc], acc[cc], 0, 0, 0);
    }

#pragma unroll
    for (int u = 0; u < 8; ++u) cadj[u] = nadj[u];
    buf ^= 1;
  }

  // Epilogue: plain stores. C/D: col=lane&15, row=q*4+reg.
  float* pp = partials + (size_t)ks * OUT_ELEMS + (size_t)rbase * GD;
#pragma unroll
  for (int cc = 0; cc < 8; ++cc)
#pragma unroll
    for (int r = 0; r < 4; ++r)
      pp[(size_t)(q * 4 + r) * GD + cc * 16 + m] = acc[cc][r];
}

// Kernel 3: out = x + sum of 4 partials (also un-poisons d_out)
__global__ __launch_bounds__(256) void reduce_kernel(const float* __restrict__ x,
                                                     const float* __restrict__ partials,
                                                     float* __restrict__ out) {
  size_t i = ((size_t)blockIdx.x * 256 + threadIdx.x) * 4;
  floatx4 v = *(const floatx4*)(x + i);
  v += *(const floatx4*)(partials + 0 * (size_t)OUT_ELEMS + i);
  v += *(const floatx4*)(partials + 1 * (size_t)OUT_ELEMS + i);
  v += *(const floatx4*)(partials + 2 * (size_t)OUT_ELEMS + i);
  v += *(const floatx4*)(partials + 3 * (size_t)OUT_ELEMS + i);
  *(floatx4*)(out + i) = v;
}

extern "C" void kernel_launch(void* const* d_in, const int* in_sizes, int n_in,
                              void* d_out, int out_size, void* d_ws, size_t ws_size,
                              hipStream_t stream) {
  const float* x = (const float*)d_in[0];
  const int* adj = (const int*)d_in[1];
  float* out = (float*)d_out;
  unsigned short* xT = (unsigned short*)d_ws;                     // 4 MiB
  float* partials = (float*)((char*)d_ws + (size_t)GN * GD * 2);  // 4 x 8 MiB

  prep_kernel<<<GN / 64, 256, 0, stream>>>(x, xT);
  gemm_kernel<<<dim3(GN / 128, KSPLIT), 512, 0, stream>>>(adj, xT, partials);
  reduce_kernel<<<OUT_ELEMS / 4 / 256, 256, 0, stream>>>(x, partials, out);
}